// Round 3
// baseline (685.979 us; speedup 1.0000x reference)
//
#include <hip/hip_runtime.h>

typedef short v8s __attribute__((ext_vector_type(8)));
typedef float v4f __attribute__((ext_vector_type(4)));

#define NSP 32768
#define ZOFF 8192            // dword offset of Z-partials region in ws

__device__ __forceinline__ unsigned short f2bf(float f) {
  union { float f; unsigned u; } v; v.f = f;
  unsigned r = v.u + 0x7fffu + ((v.u >> 16) & 1u);
  return (unsigned short)(r >> 16);
}
__device__ __forceinline__ unsigned pk(float a, float b) {
  return (unsigned)f2bf(a) | ((unsigned)f2bf(b) << 16);
}

union UF8 { v8s v; unsigned u[4]; uint4 q; };

// k-map convention used CONSISTENTLY for every A and B fragment (errors cancel):
// frag element j of lane (i16 + 16*g) <-> k = 16*(j>>2) + 4*g + (j&3)

// ---------------- prep kernel: weight fragments into ws ----------------
__global__ __launch_bounds__(512) void prep_kernel(
    const float* __restrict__ Wk, const float* __restrict__ bk,
    const float* __restrict__ Wq, const float* __restrict__ bq,
    const float* __restrict__ Wv, unsigned* __restrict__ ws) {
  __shared__ float sWk[4096], sWq[4096], sWv[4096], sbk[64], sbq[64];
  for (int i = threadIdx.x; i < 4096; i += 512) { sWk[i] = Wk[i]; sWq[i] = Wq[i]; sWv[i] = Wv[i]; }
  if (threadIdx.x < 64) { sbk[threadIdx.x] = bk[threadIdx.x]; sbq[threadIdx.x] = bq[threadIdx.x]; }
  __syncthreads();
  for (int task = threadIdx.x; task < 18 * 64; task += 512) {
    int f = task >> 6, lane = task & 63;
    int i16 = lane & 15, g = lane >> 4;
    unsigned short e[8];
    #pragma unroll
    for (int j = 0; j < 8; ++j) {
      int k = (((j >> 2) << 4) + 4 * g + (j & 3));
      float acc = 0.f;
      if (f < 8) {
        int row = ((f >> 1) << 4) + i16;
        int cc  = ((f & 1) << 5) + k;
        for (int a = 0; a < 64; ++a) acc += sWk[a * 64 + row] * sWq[a * 64 + cc];
      } else if (f < 10) {
        int c = ((f - 8) << 5) + k;
        if (i16 == 0)      { for (int a = 0; a < 64; ++a) acc += sWk[a * 64 + c] * sbq[a]; }
        else if (i16 == 1) { for (int a = 0; a < 64; ++a) acc += sbk[a] * sWq[a * 64 + c]; }
      } else {
        int c  = (((f - 10) >> 1) << 4) + i16;
        int cp = (((f - 10) & 1) << 5) + k;
        acc = sWv[c * 64 + cp];
      }
      e[j] = f2bf(acc);
    }
    unsigned* dst = ws + (size_t)(f * 64 + lane) * 4;
    dst[0] = e[0] | ((unsigned)e[1] << 16);
    dst[1] = e[2] | ((unsigned)e[3] << 16);
    dst[2] = e[4] | ((unsigned)e[5] << 16);
    dst[3] = e[6] | ((unsigned)e[7] << 16);
  }
  if (threadIdx.x == 0) {
    float beta = 0.f;
    for (int a = 0; a < 64; ++a) beta += sbk[a] * sbq[a];
    ((float*)ws)[18 * 256] = beta;
  }
}

// decode 1024-block grid: each XCD gets one contiguous (b,dc) plane, w-tiles adjacent
#define DECODE_GRID() \
  int bid = (int)blockIdx.x; \
  int L = ((bid & 7) << 7) | (bid >> 3); \
  int w0 = (L & 3) << 3; \
  int h  = (L >> 2) & 31; \
  int b  = (L >> 7) & 1; \
  int dc = L >> 8; \
  const int d0 = dc << 3; \
  const int base0 = b * 33554432 + h * 32 + w0;

#define S2L 0.18033688011112042f  /* (1/8) * log2(e) */

// ---------------- pass 1: partial Z over an 8-slice d-chunk ----------------
__global__ __launch_bounds__(512, 4) void pass1_z(
    const float* __restrict__ x, const unsigned* __restrict__ ws,
    float* __restrict__ zp) {
  __shared__ __align__(16) unsigned char Xbuf[2][16512];

  const int tid = (int)threadIdx.x;
  const int lane = tid & 63, wv = tid >> 6;
  const int i16 = lane & 15, g = lane >> 4;
  const int l8 = tid & 7, p0 = tid >> 3;
  DECODE_GRID();

  v8s fM[4][2], fUR[2];
  {
    const uint4* W4 = (const uint4*)ws;
    #pragma unroll
    for (int f = 0; f < 8; ++f) { UF8 u; u.q = W4[f * 64 + lane]; fM[f >> 1][f & 1] = u.v; }
    #pragma unroll
    for (int f = 0; f < 2; ++f) { UF8 u; u.q = W4[(8 + f) * 64 + lane]; fUR[f] = u.v; }
  }
  const float beta = ((const float*)ws)[4608];

  float sr0[8], sr1[8];
  auto issue = [&](int d) {
    const float* xp = x + base0 + d * 1024;
    #pragma unroll
    for (int i = 0; i < 8; ++i) {
      int tc = 2 * (p0 + 64 * i);
      sr0[i] = xp[(size_t)tc * NSP + l8];
      sr1[i] = xp[(size_t)(tc + 1) * NSP + l8];
    }
  };
  auto swrite = [&](int bb) {
    unsigned char* bp = &Xbuf[bb][l8 * 2064];
    #pragma unroll
    for (int i = 0; i < 8; ++i) {
      int tc = 2 * (p0 + 64 * i);
      int t = tc >> 6, c = tc & 63;
      int off = (t << 7) + (((c << 1)) ^ ((t & 7) << 4));
      *(unsigned*)(bp + off) = pk(sr0[i], sr1[i]);
    }
  };
  auto loadX = [&](int bb, v8s fX[2]) {
    const unsigned char* bp = &Xbuf[bb][wv * 2064 + (i16 << 7)];
    const int sw = (i16 & 7) << 4;
    #pragma unroll
    for (int kc = 0; kc < 2; ++kc) {
      union { v8s v; unsigned long long dd[2]; } u;
      int o = (kc << 6) + (g << 3);
      u.dd[0] = *(const unsigned long long*)(bp + (o ^ sw));
      u.dd[1] = *(const unsigned long long*)(bp + ((o + 32) ^ sw));
      fX[kc] = u.v;
    }
  };
  auto attOf = [&](const v8s fX[2]) -> v4f {
    v4f accW[4];
    #pragma unroll
    for (int tr = 0; tr < 4; ++tr) {
      v4f a = {0.f, 0.f, 0.f, 0.f};
      a = __builtin_amdgcn_mfma_f32_16x16x32_bf16(fM[tr][0], fX[0], a, 0, 0, 0);
      a = __builtin_amdgcn_mfma_f32_16x16x32_bf16(fM[tr][1], fX[1], a, 0, 0, 0);
      accW[tr] = a;
    }
    v4f au = {0.f, 0.f, 0.f, 0.f};
    au = __builtin_amdgcn_mfma_f32_16x16x32_bf16(fUR[0], fX[0], au, 0, 0, 0);
    au = __builtin_amdgcn_mfma_f32_16x16x32_bf16(fUR[1], fX[1], au, 0, 0, 0);
    float a1v = au[0] + beta;
    float a2v = au[1];
    float a2s = __shfl(a2v, i16);
    v4f att;
    #pragma unroll
    for (int j = 0; j < 4; ++j) att[j] = __shfl(a1v, 4 * g + j) + a2s;
    #pragma unroll
    for (int kc = 0; kc < 2; ++kc) {
      UF8 w;
      w.u[0] = pk(accW[2 * kc][0], accW[2 * kc][1]);
      w.u[1] = pk(accW[2 * kc][2], accW[2 * kc][3]);
      w.u[2] = pk(accW[2 * kc + 1][0], accW[2 * kc + 1][1]);
      w.u[3] = pk(accW[2 * kc + 1][2], accW[2 * kc + 1][3]);
      att = __builtin_amdgcn_mfma_f32_16x16x32_bf16(fX[kc], w.v, att, 0, 0, 0);
    }
    return att;
  };

  float Z[4] = {0.f, 0.f, 0.f, 0.f};
  issue(d0); swrite(0);
  int cur = 0;
  for (int i = 0; i < 8; ++i) {
    __syncthreads();
    if (i < 7) issue(d0 + i + 1);
    v8s fX[2]; loadX(cur, fX);
    v4f att = attOf(fX);
    #pragma unroll
    for (int j = 0; j < 4; ++j) Z[j] += exp2f(att[j] * S2L);
    if (i < 7) swrite(cur ^ 1);
    cur ^= 1;
  }
  const int locg = b * 1024 + h * 32 + w0 + wv;
  float* zdst = zp + ((size_t)(dc * 2048 + locg) << 8);
  #pragma unroll
  for (int j = 0; j < 4; ++j) zdst[(4 * g + j) * 16 + i16] = Z[j];
}

// ---------------- pass 2: P, v, feat, out for an 8-slice d-chunk ----------------
__global__ __launch_bounds__(512, 4) void pass2_out(
    const float* __restrict__ x, const float* __restrict__ bv,
    const unsigned* __restrict__ ws, const float* __restrict__ zp,
    float* __restrict__ out) {
  __shared__ __align__(16) unsigned char Xbuf[2][16512];
  __shared__ float Fb[8736];

  const int tid = (int)threadIdx.x;
  const int lane = tid & 63, wv = tid >> 6;
  const int i16 = lane & 15, g = lane >> 4;
  const int l8 = tid & 7, p0 = tid >> 3;
  DECODE_GRID();

  v8s fM[4][2], fUR[2], fWv[4][2];
  {
    const uint4* W4 = (const uint4*)ws;
    #pragma unroll
    for (int f = 0; f < 8; ++f) { UF8 u; u.q = W4[f * 64 + lane]; fM[f >> 1][f & 1] = u.v; }
    #pragma unroll
    for (int f = 0; f < 2; ++f) { UF8 u; u.q = W4[(8 + f) * 64 + lane]; fUR[f] = u.v; }
    #pragma unroll
    for (int f = 0; f < 8; ++f) { UF8 u; u.q = W4[(10 + f) * 64 + lane]; fWv[f >> 1][f & 1] = u.v; }
  }
  const float beta = ((const float*)ws)[4608];
  float bvv[4];
  #pragma unroll
  for (int tn = 0; tn < 4; ++tn) bvv[tn] = bv[i16 + 16 * tn];

  // sum the 4 d-chunk partials -> 1/Z
  const int locg = b * 1024 + h * 32 + w0 + wv;
  float iZ[4];
  #pragma unroll
  for (int j = 0; j < 4; ++j) {
    float s = 0.f;
    #pragma unroll
    for (int dc2 = 0; dc2 < 4; ++dc2)
      s += zp[((size_t)(dc2 * 2048 + locg) << 8) + (4 * g + j) * 16 + i16];
    iZ[j] = 1.f / s;
  }

  float sr0[8], sr1[8];
  auto issue = [&](int d) {
    const float* xp = x + base0 + d * 1024;
    #pragma unroll
    for (int i = 0; i < 8; ++i) {
      int tc = 2 * (p0 + 64 * i);
      sr0[i] = xp[(size_t)tc * NSP + l8];
      sr1[i] = xp[(size_t)(tc + 1) * NSP + l8];
    }
  };
  auto swrite = [&](int bb) {
    unsigned char* bp = &Xbuf[bb][l8 * 2064];
    #pragma unroll
    for (int i = 0; i < 8; ++i) {
      int tc = 2 * (p0 + 64 * i);
      int t = tc >> 6, c = tc & 63;
      int off = (t << 7) + (((c << 1)) ^ ((t & 7) << 4));
      *(unsigned*)(bp + off) = pk(sr0[i], sr1[i]);
    }
  };
  auto loadX = [&](int bb, v8s fX[2]) {
    const unsigned char* bp = &Xbuf[bb][wv * 2064 + (i16 << 7)];
    const int sw = (i16 & 7) << 4;
    #pragma unroll
    for (int kc = 0; kc < 2; ++kc) {
      union { v8s v; unsigned long long dd[2]; } u;
      int o = (kc << 6) + (g << 3);
      u.dd[0] = *(const unsigned long long*)(bp + (o ^ sw));
      u.dd[1] = *(const unsigned long long*)(bp + ((o + 32) ^ sw));
      fX[kc] = u.v;
    }
  };
  auto attOf = [&](const v8s fX[2]) -> v4f {
    v4f accW[4];
    #pragma unroll
    for (int tr = 0; tr < 4; ++tr) {
      v4f a = {0.f, 0.f, 0.f, 0.f};
      a = __builtin_amdgcn_mfma_f32_16x16x32_bf16(fM[tr][0], fX[0], a, 0, 0, 0);
      a = __builtin_amdgcn_mfma_f32_16x16x32_bf16(fM[tr][1], fX[1], a, 0, 0, 0);
      accW[tr] = a;
    }
    v4f au = {0.f, 0.f, 0.f, 0.f};
    au = __builtin_amdgcn_mfma_f32_16x16x32_bf16(fUR[0], fX[0], au, 0, 0, 0);
    au = __builtin_amdgcn_mfma_f32_16x16x32_bf16(fUR[1], fX[1], au, 0, 0, 0);
    float a1v = au[0] + beta;
    float a2v = au[1];
    float a2s = __shfl(a2v, i16);
    v4f att;
    #pragma unroll
    for (int j = 0; j < 4; ++j) att[j] = __shfl(a1v, 4 * g + j) + a2s;
    #pragma unroll
    for (int kc = 0; kc < 2; ++kc) {
      UF8 w;
      w.u[0] = pk(accW[2 * kc][0], accW[2 * kc][1]);
      w.u[1] = pk(accW[2 * kc][2], accW[2 * kc][3]);
      w.u[2] = pk(accW[2 * kc + 1][0], accW[2 * kc + 1][1]);
      w.u[3] = pk(accW[2 * kc + 1][2], accW[2 * kc + 1][3]);
      att = __builtin_amdgcn_mfma_f32_16x16x32_bf16(fX[kc], w.v, att, 0, 0, 0);
    }
    return att;
  };

  issue(d0); swrite(0);
  int cur = 0;
  for (int i = 0; i < 8; ++i) {
    __syncthreads();
    if (i < 7) issue(d0 + i + 1);
    v8s fX[2]; loadX(cur, fX);
    v4f att = attOf(fX);
    float p[4];
    #pragma unroll
    for (int j = 0; j < 4; ++j) p[j] = exp2f(att[j] * S2L) * iZ[j];
    v4f accV[4];
    #pragma unroll
    for (int tn = 0; tn < 4; ++tn) {
      v4f a = {bvv[tn], bvv[tn], bvv[tn], bvv[tn]};
      a = __builtin_amdgcn_mfma_f32_16x16x32_bf16(fX[0], fWv[tn][0], a, 0, 0, 0);
      a = __builtin_amdgcn_mfma_f32_16x16x32_bf16(fX[1], fWv[tn][1], a, 0, 0, 0);
      accV[tn] = a;
    }
    UF8 fP; fP.u[0] = pk(p[0], p[1]); fP.u[1] = pk(p[2], p[3]); fP.u[2] = 0; fP.u[3] = 0;
    #pragma unroll
    for (int tn = 0; tn < 4; ++tn) {
      UF8 fV; fV.u[0] = pk(accV[tn][0], accV[tn][1]); fV.u[1] = pk(accV[tn][2], accV[tn][3]);
      fV.u[2] = 0; fV.u[3] = 0;
      v4f ft = {0.f, 0.f, 0.f, 0.f};
      ft = __builtin_amdgcn_mfma_f32_16x16x32_bf16(fP.v, fV.v, ft, 0, 0, 0);
      #pragma unroll
      for (int j = 0; j < 4; ++j)
        Fb[wv * 1092 + (4 * g + j) * 68 + i16 + 16 * tn] = ft[j];
    }
    if (i < 7) swrite(cur ^ 1);
    __syncthreads();
    float* op = out + base0 + (d0 + i) * 1024;
    #pragma unroll
    for (int ii = 0; ii < 16; ++ii) {
      int e = ii * 512 + tid;
      int le = e & 7, sc = e >> 3;
      op[(size_t)sc * NSP + le] = Fb[le * 1092 + ((sc >> 6) * 68) + (sc & 63)];
    }
    cur ^= 1;
  }
}

extern "C" void kernel_launch(void* const* d_in, const int* in_sizes, int n_in,
                              void* d_out, int out_size, void* d_ws, size_t ws_size,
                              hipStream_t stream) {
  const float* x  = (const float*)d_in[0];
  const float* Wk = (const float*)d_in[1];
  const float* bk = (const float*)d_in[2];
  const float* Wq = (const float*)d_in[3];
  const float* bq = (const float*)d_in[4];
  const float* Wv = (const float*)d_in[5];
  const float* bv = (const float*)d_in[6];
  float* out = (float*)d_out;
  unsigned* ws = (unsigned*)d_ws;
  float* zp = (float*)d_ws + ZOFF;

  prep_kernel<<<1, 512, 0, stream>>>(Wk, bk, Wq, bq, Wv, ws);
  pass1_z<<<1024, 512, 0, stream>>>(x, ws, zp);
  pass2_out<<<1024, 512, 0, stream>>>(x, bv, ws, zp, out);
}

// Round 4
// 322.306 us; speedup vs baseline: 2.1283x; 2.1283x over previous
//
#include <hip/hip_runtime.h>

typedef short v8s __attribute__((ext_vector_type(8)));
typedef float v4f __attribute__((ext_vector_type(4)));
typedef float v2f __attribute__((ext_vector_type(2)));

#define NSP 32768
#define ZOFF 8192            // dword offset of Z-partials region in ws
#define XSTR 2056            // bytes per location in Xbuf (8B aligned, bank-staggered)
#define FSTR 34              // dwords per Fb row (even -> b64-aligned pairs)

__device__ __forceinline__ unsigned short f2bf(float f) {
  union { float f; unsigned u; } v; v.f = f;
  unsigned r = v.u + 0x7fffu + ((v.u >> 16) & 1u);
  return (unsigned short)(r >> 16);
}
__device__ __forceinline__ unsigned pk(float a, float b) {
  return (unsigned)f2bf(a) | ((unsigned)f2bf(b) << 16);
}

union UF8 { v8s v; unsigned u[4]; uint4 q; };

// k-map convention used CONSISTENTLY for every A and B fragment (errors cancel):
// frag element j of lane (i16 + 16*g) <-> k = 16*(j>>2) + 4*g + (j&3)

__global__ __launch_bounds__(512) void prep_kernel(
    const float* __restrict__ Wk, const float* __restrict__ bk,
    const float* __restrict__ Wq, const float* __restrict__ bq,
    const float* __restrict__ Wv, unsigned* __restrict__ ws) {
  __shared__ float sWk[4096], sWq[4096], sWv[4096], sbk[64], sbq[64];
  for (int i = threadIdx.x; i < 4096; i += 512) { sWk[i] = Wk[i]; sWq[i] = Wq[i]; sWv[i] = Wv[i]; }
  if (threadIdx.x < 64) { sbk[threadIdx.x] = bk[threadIdx.x]; sbq[threadIdx.x] = bq[threadIdx.x]; }
  __syncthreads();
  for (int task = threadIdx.x; task < 18 * 64; task += 512) {
    int f = task >> 6, lane = task & 63;
    int i16 = lane & 15, g = lane >> 4;
    unsigned short e[8];
    #pragma unroll
    for (int j = 0; j < 8; ++j) {
      int k = (((j >> 2) << 4) + 4 * g + (j & 3));
      float acc = 0.f;
      if (f < 8) {
        int row = ((f >> 1) << 4) + i16;
        int cc  = ((f & 1) << 5) + k;
        for (int a = 0; a < 64; ++a) acc += sWk[a * 64 + row] * sWq[a * 64 + cc];
      } else if (f < 10) {
        int c = ((f - 8) << 5) + k;
        if (i16 == 0)      { for (int a = 0; a < 64; ++a) acc += sWk[a * 64 + c] * sbq[a]; }
        else if (i16 == 1) { for (int a = 0; a < 64; ++a) acc += sbk[a] * sWq[a * 64 + c]; }
      } else {
        int c  = (((f - 10) >> 1) << 4) + i16;
        int cp = (((f - 10) & 1) << 5) + k;
        acc = sWv[c * 64 + cp];
      }
      e[j] = f2bf(acc);
    }
    unsigned* dst = ws + (size_t)(f * 64 + lane) * 4;
    dst[0] = e[0] | ((unsigned)e[1] << 16);
    dst[1] = e[2] | ((unsigned)e[3] << 16);
    dst[2] = e[4] | ((unsigned)e[5] << 16);
    dst[3] = e[6] | ((unsigned)e[7] << 16);
  }
  if (threadIdx.x == 0) {
    float beta = 0.f;
    for (int a = 0; a < 64; ++a) beta += sbk[a] * sbq[a];
    ((float*)ws)[18 * 256] = beta;
  }
}

#define S2L 0.18033688011112042f  /* (1/8) * log2(e) */

// grid decode: 256 blocks; XCD = bid%8 = (dc,b) -> per-XCD 4KB-contiguous streams
#define DECODE_GRID() \
  int bid = (int)blockIdx.x; \
  int b = bid & 1, dc = (bid >> 1) & 3, h = bid >> 3; \
  const int d0 = dc << 3; \
  const size_t base0 = (size_t)b * 33554432 + h * 32;

// staging: thread holds row-pairs (2rp, 2rp+1) x float2 (w=2w2, 2w2+1); full 128B lines
#define STAGE_DEFS() \
  const int w2 = tid & 15; \
  const int rp0 = tid >> 4; \
  v2f sA[16], sB[16]; \
  auto issueRegs = [&](int d) { \
    const float* xp = x + base0 + (size_t)d * 1024; \
    _Pragma("unroll") \
    for (int i = 0; i < 16; ++i) { \
      int rp = (i << 5) + rp0; \
      const float* r0 = xp + (size_t)(2 * rp) * NSP + 2 * w2; \
      sA[i] = *(const v2f*)r0; \
      sB[i] = *(const v2f*)(r0 + NSP); \
    } \
  }; \
  auto writeLds = [&]() { \
    _Pragma("unroll") \
    for (int i = 0; i < 16; ++i) { \
      int rp = (i << 5) + rp0; \
      int t = rp >> 5, c = (rp & 31) << 1; \
      int off = (t << 7) + (((c << 1)) ^ ((t & 7) << 4)); \
      *(unsigned*)(&Xbuf[(2 * w2) * XSTR + off])     = pk(sA[i].x, sB[i].x); \
      *(unsigned*)(&Xbuf[(2 * w2 + 1) * XSTR + off]) = pk(sA[i].y, sB[i].y); \
    } \
  };

#define LOADX_DEF() \
  auto loadX = [&](int loc, v8s fX[2]) { \
    const unsigned char* bp = &Xbuf[loc * XSTR + (i16 << 7)]; \
    const int sw = (i16 & 7) << 4; \
    _Pragma("unroll") \
    for (int kc = 0; kc < 2; ++kc) { \
      union { v8s v; unsigned long long dd[2]; } u; \
      int o = (kc << 6) + (g << 3); \
      u.dd[0] = *(const unsigned long long*)(bp + (o ^ sw)); \
      u.dd[1] = *(const unsigned long long*)(bp + ((o + 32) ^ sw)); \
      fX[kc] = u.v; \
    } \
  };

#define ATTOF_DEF() \
  auto attOf = [&](const v8s fX[2]) -> v4f { \
    v4f accW[4]; \
    _Pragma("unroll") \
    for (int tr = 0; tr < 4; ++tr) { \
      v4f a = {0.f, 0.f, 0.f, 0.f}; \
      a = __builtin_amdgcn_mfma_f32_16x16x32_bf16(fM[tr][0], fX[0], a, 0, 0, 0); \
      a = __builtin_amdgcn_mfma_f32_16x16x32_bf16(fM[tr][1], fX[1], a, 0, 0, 0); \
      accW[tr] = a; \
    } \
    v4f au = {0.f, 0.f, 0.f, 0.f}; \
    au = __builtin_amdgcn_mfma_f32_16x16x32_bf16(fUR[0], fX[0], au, 0, 0, 0); \
    au = __builtin_amdgcn_mfma_f32_16x16x32_bf16(fUR[1], fX[1], au, 0, 0, 0); \
    float a1v = au[0] + beta; \
    float a2v = au[1]; \
    float a2s = __shfl(a2v, i16); \
    v4f att; \
    _Pragma("unroll") \
    for (int j = 0; j < 4; ++j) att[j] = __shfl(a1v, 4 * g + j) + a2s; \
    _Pragma("unroll") \
    for (int kc = 0; kc < 2; ++kc) { \
      UF8 w; \
      w.u[0] = pk(accW[2 * kc][0], accW[2 * kc][1]); \
      w.u[1] = pk(accW[2 * kc][2], accW[2 * kc][3]); \
      w.u[2] = pk(accW[2 * kc + 1][0], accW[2 * kc + 1][1]); \
      w.u[3] = pk(accW[2 * kc + 1][2], accW[2 * kc + 1][3]); \
      att = __builtin_amdgcn_mfma_f32_16x16x32_bf16(fX[kc], w.v, att, 0, 0, 0); \
    } \
    return att; \
  };

// ---------------- pass 1: partial Z over an 8-slice d-chunk ----------------
__global__ __launch_bounds__(512) void pass1_z(
    const float* __restrict__ x, const unsigned* __restrict__ ws,
    float* __restrict__ zp) {
  __shared__ __align__(16) unsigned char Xbuf[32 * XSTR];

  const int tid = (int)threadIdx.x;
  const int lane = tid & 63, wv = tid >> 6;
  const int i16 = lane & 15, g = lane >> 4;
  DECODE_GRID();

  v8s fM[4][2], fUR[2];
  {
    const uint4* W4 = (const uint4*)ws;
    #pragma unroll
    for (int f = 0; f < 8; ++f) { UF8 u; u.q = W4[f * 64 + lane]; fM[f >> 1][f & 1] = u.v; }
    #pragma unroll
    for (int f = 0; f < 2; ++f) { UF8 u; u.q = W4[(8 + f) * 64 + lane]; fUR[f] = u.v; }
  }
  const float beta = ((const float*)ws)[4608];

  STAGE_DEFS();
  LOADX_DEF();
  ATTOF_DEF();

  float Z[4][4] = {};
  issueRegs(d0);
  for (int ii = 0; ii < 8; ++ii) {
    __syncthreads();
    writeLds();
    if (ii < 7) issueRegs(d0 + ii + 1);
    __syncthreads();
    #pragma unroll
    for (int l = 0; l < 4; ++l) {
      v8s fX[2]; loadX(4 * wv + l, fX);
      v4f att = attOf(fX);
      #pragma unroll
      for (int j = 0; j < 4; ++j) Z[l][j] += exp2f(att[j] * S2L);
    }
  }
  const int locg = b * 1024 + h * 32 + 4 * wv;
  #pragma unroll
  for (int l = 0; l < 4; ++l)
    #pragma unroll
    for (int j = 0; j < 4; ++j)
      zp[(((size_t)dc * 2048 + locg + l) << 8) + (4 * g + j) * 16 + i16] = Z[l][j];
}

// ---------------- pass 2: P, v, feat, out (reverse d for L3 reuse) ----------------
__global__ __launch_bounds__(512) void pass2_out(
    const float* __restrict__ x, const float* __restrict__ bv,
    const unsigned* __restrict__ ws, const float* __restrict__ zp,
    float* __restrict__ out) {
  __shared__ __align__(16) unsigned char Xbuf[32 * XSTR];
  __shared__ float Fb[512 * FSTR];

  const int tid = (int)threadIdx.x;
  const int lane = tid & 63, wv = tid >> 6;
  const int i16 = lane & 15, g = lane >> 4;
  DECODE_GRID();

  v8s fM[4][2], fUR[2], fWv[4][2];
  {
    const uint4* W4 = (const uint4*)ws;
    #pragma unroll
    for (int f = 0; f < 8; ++f) { UF8 u; u.q = W4[f * 64 + lane]; fM[f >> 1][f & 1] = u.v; }
    #pragma unroll
    for (int f = 0; f < 2; ++f) { UF8 u; u.q = W4[(8 + f) * 64 + lane]; fUR[f] = u.v; }
    #pragma unroll
    for (int f = 0; f < 8; ++f) { UF8 u; u.q = W4[(10 + f) * 64 + lane]; fWv[f >> 1][f & 1] = u.v; }
  }
  const float beta = ((const float*)ws)[4608];
  float bvv[4];
  #pragma unroll
  for (int tn = 0; tn < 4; ++tn) bvv[tn] = bv[i16 + 16 * tn];

  // 1/Z from the 4 chunk partials
  const int locg = b * 1024 + h * 32 + 4 * wv;
  float iZ[4][4];
  #pragma unroll
  for (int l = 0; l < 4; ++l)
    #pragma unroll
    for (int j = 0; j < 4; ++j) {
      float s = 0.f;
      #pragma unroll
      for (int c2 = 0; c2 < 4; ++c2)
        s += zp[(((size_t)c2 * 2048 + locg + l) << 8) + (4 * g + j) * 16 + i16];
      iZ[l][j] = 1.f / s;
    }

  STAGE_DEFS();
  LOADX_DEF();
  ATTOF_DEF();

  auto storeHalf = [&](int half, int d) {
    float* op = out + base0 + (size_t)d * 1024 + ((size_t)half << 5) * NSP;
    const int w4 = tid & 7, rr = tid >> 3;
    #pragma unroll
    for (int ro = 0; ro < 8; ++ro) {
      int r = (ro << 6) + rr;
      int s = r >> 5, ci = r & 31;
      int v = ((r >> 7) & 1) << 2;
      int bse = r * FSTR + ((w4 << 2) ^ v);
      float4 val;
      val.x = Fb[bse]; val.y = Fb[bse + 1]; val.z = Fb[bse + 2]; val.w = Fb[bse + 3];
      *(float4*)(op + (size_t)(s * 64 + ci) * NSP + (w4 << 2)) = val;
    }
  };

  issueRegs(d0 + 7);
  for (int ii = 0; ii < 8; ++ii) {
    const int d = d0 + 7 - ii;                 // reverse order: ride pass1's L3 tail
    __syncthreads();
    writeLds();
    if (ii < 7) issueRegs(d - 1);
    __syncthreads();

    unsigned fPs[4][2];
    // ---- phase A: att, P, v(tn 0,1), feat -> Fb (c in [0,32)) ----
    #pragma unroll
    for (int l = 0; l < 4; ++l) {
      const int w = 4 * wv + l;
      v8s fX[2]; loadX(w, fX);
      v4f att = attOf(fX);
      float p[4];
      #pragma unroll
      for (int j = 0; j < 4; ++j) p[j] = exp2f(att[j] * S2L) * iZ[l][j];
      fPs[l][0] = pk(p[0], p[1]); fPs[l][1] = pk(p[2], p[3]);
      #pragma unroll
      for (int tn = 0; tn < 2; ++tn) {
        v4f a = {bvv[tn], bvv[tn], bvv[tn], bvv[tn]};
        a = __builtin_amdgcn_mfma_f32_16x16x32_bf16(fX[0], fWv[tn][0], a, 0, 0, 0);
        a = __builtin_amdgcn_mfma_f32_16x16x32_bf16(fX[1], fWv[tn][1], a, 0, 0, 0);
        UF8 fV; fV.u[0] = pk(a[0], a[1]); fV.u[1] = pk(a[2], a[3]); fV.u[2] = 0; fV.u[3] = 0;
        UF8 fP; fP.u[0] = fPs[l][0]; fP.u[1] = fPs[l][1]; fP.u[2] = 0; fP.u[3] = 0;
        v4f ft = {0.f, 0.f, 0.f, 0.f};
        ft = __builtin_amdgcn_mfma_f32_16x16x32_bf16(fP.v, fV.v, ft, 0, 0, 0);
        #pragma unroll
        for (int j = 0; j < 4; ++j) {
          int r = (4 * g + j) * 32 + i16 + 16 * tn;
          Fb[r * FSTR + (w ^ (((r >> 7) & 1) << 2))] = ft[j];
        }
      }
    }
    __syncthreads();
    storeHalf(0, d);
    __syncthreads();
    // ---- phase B: v(tn 2,3), feat -> Fb (c in [32,64)) ----
    #pragma unroll
    for (int l = 0; l < 4; ++l) {
      const int w = 4 * wv + l;
      v8s fX[2]; loadX(w, fX);
      #pragma unroll
      for (int tn = 2; tn < 4; ++tn) {
        v4f a = {bvv[tn], bvv[tn], bvv[tn], bvv[tn]};
        a = __builtin_amdgcn_mfma_f32_16x16x32_bf16(fX[0], fWv[tn][0], a, 0, 0, 0);
        a = __builtin_amdgcn_mfma_f32_16x16x32_bf16(fX[1], fWv[tn][1], a, 0, 0, 0);
        UF8 fV; fV.u[0] = pk(a[0], a[1]); fV.u[1] = pk(a[2], a[3]); fV.u[2] = 0; fV.u[3] = 0;
        UF8 fP; fP.u[0] = fPs[l][0]; fP.u[1] = fPs[l][1]; fP.u[2] = 0; fP.u[3] = 0;
        v4f ft = {0.f, 0.f, 0.f, 0.f};
        ft = __builtin_amdgcn_mfma_f32_16x16x32_bf16(fP.v, fV.v, ft, 0, 0, 0);
        #pragma unroll
        for (int j = 0; j < 4; ++j) {
          int r = (4 * g + j) * 32 + i16 + 16 * (tn - 2);
          Fb[r * FSTR + (w ^ (((r >> 7) & 1) << 2))] = ft[j];
        }
      }
    }
    __syncthreads();
    storeHalf(1, d);
  }
}

extern "C" void kernel_launch(void* const* d_in, const int* in_sizes, int n_in,
                              void* d_out, int out_size, void* d_ws, size_t ws_size,
                              hipStream_t stream) {
  const float* x  = (const float*)d_in[0];
  const float* Wk = (const float*)d_in[1];
  const float* bk = (const float*)d_in[2];
  const float* Wq = (const float*)d_in[3];
  const float* bq = (const float*)d_in[4];
  const float* Wv = (const float*)d_in[5];
  const float* bv = (const float*)d_in[6];
  float* out = (float*)d_out;
  unsigned* ws = (unsigned*)d_ws;
  float* zp = (float*)d_ws + ZOFF;

  prep_kernel<<<1, 512, 0, stream>>>(Wk, bk, Wq, bq, Wv, ws);
  pass1_z<<<256, 512, 0, stream>>>(x, ws, zp);
  pass2_out<<<256, 512, 0, stream>>>(x, bv, ws, zp, out);
}